// Round 1
// baseline (1144.562 us; speedup 1.0000x reference)
//
#include <hip/hip_runtime.h>
#include <hip/hip_bf16.h>

typedef __attribute__((ext_vector_type(8))) short short8;
typedef __attribute__((ext_vector_type(4))) float f32x4;

#define DN   128
#define DE   64
#define DIN  192
#define HID  256
#define OUTD 128
#define TE   64      // edges per block
#define MSG_LD 200   // 192 + 8 pad (bf16 elems): row stride 400B = 100 dwords -> 4-bank shift/row
#define H_LD   264   // 256 + 8 pad: row stride 528B = 132 dwords -> 4-bank shift/row

static __device__ __forceinline__ unsigned short f2b(float f) {
    // round-to-nearest-even fp32 -> bf16 (inputs are finite)
    unsigned int u = __float_as_uint(f);
    u += 0x7fffu + ((u >> 16) & 1u);
    return (unsigned short)(u >> 16);
}

// Repack weights to bf16 fragment-ready layout: Wp[((k/32)*Ncols + n)*32 + (k%32)]
__global__ void pack_w_kernel(const float* __restrict__ W, unsigned short* __restrict__ Wp,
                              int K, int Ncols) {
    int idx = blockIdx.x * blockDim.x + threadIdx.x;
    if (idx >= K * Ncols) return;
    int k = idx / Ncols, n = idx - k * Ncols;
    Wp[(((k >> 5) * Ncols + n) << 5) + (k & 31)] = f2b(W[idx]);
}

// Partition edges: row<col -> list_out, row>col -> list_in (row==col dropped).
__global__ void partition_kernel(const int* __restrict__ ei, int E,
                                 int* __restrict__ cnt,
                                 int* __restrict__ list_out, int* __restrict__ list_in) {
    int e = blockIdx.x * blockDim.x + threadIdx.x;
    bool valid = e < E;
    int r = 0, c = 0;
    if (valid) { r = ei[e]; c = ei[E + e]; }
    bool po = valid && (r < c);
    bool pi = valid && (r > c);
    int lane = threadIdx.x & 63;
    {
        unsigned long long m = __ballot(po);
        if (m) {
            int leader = __ffsll(m) - 1;
            int base = 0;
            if (lane == leader) base = atomicAdd(&cnt[0], __popcll(m));
            base = __shfl(base, leader, 64);
            if (po) list_out[base + __popcll(m & ((1ull << lane) - 1ull))] = e;
        }
    }
    {
        unsigned long long m = __ballot(pi);
        if (m) {
            int leader = __ffsll(m) - 1;
            int base = 0;
            if (lane == leader) base = atomicAdd(&cnt[1], __popcll(m));
            base = __shfl(base, leader, 64);
            if (pi) list_in[base + __popcll(m & ((1ull << lane) - 1ull))] = e;
        }
    }
}

__global__ __launch_bounds__(256, 2)
void mlp_scatter_kernel(const float* __restrict__ x,
                        const int* __restrict__ ei,
                        const float* __restrict__ ea,
                        const unsigned short* __restrict__ W1p_out,
                        const unsigned short* __restrict__ W1p_in,
                        const float* __restrict__ b1_out,
                        const float* __restrict__ b1_in,
                        const unsigned short* __restrict__ W2p_out,
                        const unsigned short* __restrict__ W2p_in,
                        const float* __restrict__ b2_out,
                        const float* __restrict__ b2_in,
                        const int* __restrict__ list_out,
                        const int* __restrict__ list_in,
                        const int* __restrict__ cnt,
                        float* __restrict__ out,
                        int E, int nbpb) {
    __shared__ __align__(16) unsigned short s_msg[TE * MSG_LD];  // 25600 B
    __shared__ __align__(16) unsigned short s_h[TE * H_LD];      // 33792 B
    __shared__ int s_eid[TE], s_dest[TE], s_col[TE];

    const int branch = (blockIdx.x >= nbpb) ? 1 : 0;   // 0 = out-flow, 1 = in-flow
    const int lb = blockIdx.x - branch * nbpb;
    const int count = cnt[branch];
    if (lb * TE >= count) return;
    const int* list            = branch ? list_in : list_out;
    const unsigned short* W1p  = branch ? W1p_in  : W1p_out;
    const float* b1            = branch ? b1_in   : b1_out;
    const unsigned short* W2p  = branch ? W2p_in  : W2p_out;
    const float* b2            = branch ? b2_in   : b2_out;
    const int colbase          = branch ? 0 : OUTD;  // concat(flow_in, flow_out)

    const int tid = threadIdx.x;
    if (tid < TE) {
        int idx = lb * TE + tid;
        int e = (idx < count) ? list[idx] : -1;
        s_eid[tid]  = e;
        s_dest[tid] = (e >= 0) ? ei[e] : -1;       // row = scatter dest
        s_col[tid]  = (e >= 0) ? ei[E + e] : 0;    // col = gather src
    }
    __syncthreads();

    // Gather msg = concat(x[col], edge_attr[e]) as bf16 into LDS. 64 edges x 48 float4.
    for (int i = tid; i < TE * 48; i += 256) {
        int le = i / 48;
        int q  = i - le * 48;
        int e  = s_eid[le];
        float4 v = make_float4(0.f, 0.f, 0.f, 0.f);
        if (e >= 0) {
            if (q < 32) v = reinterpret_cast<const float4*>(x)[(size_t)s_col[le] * 32 + q];
            else        v = reinterpret_cast<const float4*>(ea)[(size_t)e * 16 + (q - 32)];
        }
        unsigned int lo = (unsigned int)f2b(v.x) | ((unsigned int)f2b(v.y) << 16);
        unsigned int hi = (unsigned int)f2b(v.z) | ((unsigned int)f2b(v.w) << 16);
        *reinterpret_cast<uint2*>(&s_msg[le * MSG_LD + q * 4]) = make_uint2(lo, hi);
    }
    __syncthreads();

    const int wave = tid >> 6;
    const int lane = tid & 63;
    const int ln   = lane & 15;
    const int quad = lane >> 4;

    // ---- GEMM1: h = relu(msg @ W1 + b1).  M=64, N=256 (64/wave), K=192.
    {
        const int nbase = wave * 64;
        float bias[4];
        #pragma unroll
        for (int t = 0; t < 4; ++t) bias[t] = b1[nbase + t * 16 + ln];
        f32x4 acc[4][4];
        #pragma unroll
        for (int mt = 0; mt < 4; ++mt)
            #pragma unroll
            for (int t = 0; t < 4; ++t)
                acc[mt][t] = (f32x4){bias[t], bias[t], bias[t], bias[t]};
        #pragma unroll
        for (int kt = 0; kt < DIN / 32; ++kt) {
            short8 a[4], b[4];
            #pragma unroll
            for (int mt = 0; mt < 4; ++mt)
                a[mt] = *reinterpret_cast<const short8*>(
                    &s_msg[(mt * 16 + ln) * MSG_LD + kt * 32 + quad * 8]);
            #pragma unroll
            for (int t = 0; t < 4; ++t)
                b[t] = *reinterpret_cast<const short8*>(
                    &W1p[((kt * HID + nbase + t * 16 + ln) << 5) + quad * 8]);
            #pragma unroll
            for (int mt = 0; mt < 4; ++mt)
                #pragma unroll
                for (int t = 0; t < 4; ++t)
                    acc[mt][t] = __builtin_amdgcn_mfma_f32_16x16x32_bf16(a[mt], b[t], acc[mt][t], 0, 0, 0);
        }
        // ReLU -> bf16 h in LDS. C/D map: col = lane&15, row = quad*4 + reg.
        #pragma unroll
        for (int mt = 0; mt < 4; ++mt)
            #pragma unroll
            for (int t = 0; t < 4; ++t) {
                int ncol = nbase + t * 16 + ln;
                #pragma unroll
                for (int r = 0; r < 4; ++r) {
                    int m = mt * 16 + quad * 4 + r;
                    float v = acc[mt][t][r];
                    s_h[m * H_LD + ncol] = f2b(v > 0.f ? v : 0.f);
                }
            }
    }
    __syncthreads();

    // ---- GEMM2: o = h @ W2 + b2.  M=64, N=128 (32/wave), K=256. Scatter-add by row.
    {
        const int nbase = wave * 32;
        float bias2[2];
        #pragma unroll
        for (int t = 0; t < 2; ++t) bias2[t] = b2[nbase + t * 16 + ln];
        f32x4 acc2[4][2];
        #pragma unroll
        for (int mt = 0; mt < 4; ++mt)
            #pragma unroll
            for (int t = 0; t < 2; ++t)
                acc2[mt][t] = (f32x4){bias2[t], bias2[t], bias2[t], bias2[t]};
        #pragma unroll
        for (int kt = 0; kt < HID / 32; ++kt) {
            short8 a[4], b[2];
            #pragma unroll
            for (int mt = 0; mt < 4; ++mt)
                a[mt] = *reinterpret_cast<const short8*>(
                    &s_h[(mt * 16 + ln) * H_LD + kt * 32 + quad * 8]);
            #pragma unroll
            for (int t = 0; t < 2; ++t)
                b[t] = *reinterpret_cast<const short8*>(
                    &W2p[((kt * OUTD + nbase + t * 16 + ln) << 5) + quad * 8]);
            #pragma unroll
            for (int mt = 0; mt < 4; ++mt)
                #pragma unroll
                for (int t = 0; t < 2; ++t)
                    acc2[mt][t] = __builtin_amdgcn_mfma_f32_16x16x32_bf16(a[mt], b[t], acc2[mt][t], 0, 0, 0);
        }
        #pragma unroll
        for (int mt = 0; mt < 4; ++mt) {
            #pragma unroll
            for (int r = 0; r < 4; ++r) {
                int m = mt * 16 + quad * 4 + r;
                int dest = s_dest[m];
                if (dest >= 0) {
                    float* orow = out + (size_t)dest * (2 * OUTD) + colbase + nbase + ln;
                    atomicAdd(orow,      acc2[mt][0][r]);
                    atomicAdd(orow + 16, acc2[mt][1][r]);
                }
            }
        }
    }
}

extern "C" void kernel_launch(void* const* d_in, const int* in_sizes, int n_in,
                              void* d_out, int out_size, void* d_ws, size_t ws_size,
                              hipStream_t stream) {
    const float* x   = (const float*)d_in[0];
    const int*   ei  = (const int*)d_in[1];
    const float* ea  = (const float*)d_in[2];
    const float* W1o = (const float*)d_in[3];
    const float* b1o = (const float*)d_in[4];
    const float* W2o = (const float*)d_in[5];
    const float* b2o = (const float*)d_in[6];
    const float* W1i = (const float*)d_in[7];
    const float* b1i = (const float*)d_in[8];
    const float* W2i = (const float*)d_in[9];
    const float* b2i = (const float*)d_in[10];
    float* out = (float*)d_out;
    const int E = in_sizes[1] / 2;

    // workspace layout
    char* ws = (char*)d_ws;
    int* cnt      = (int*)ws;                                  // 2 counters
    int* list_out = (int*)(ws + 256);
    int* list_in  = list_out + E;
    unsigned short* W1po = (unsigned short*)(ws + 256 + (size_t)2 * E * sizeof(int));
    unsigned short* W1pi = W1po + DIN * HID;
    unsigned short* W2po = W1pi + DIN * HID;
    unsigned short* W2pi = W2po + HID * OUTD;

    hipMemsetAsync(d_out, 0, (size_t)out_size * sizeof(float), stream);
    hipMemsetAsync(cnt, 0, 2 * sizeof(int), stream);

    pack_w_kernel<<<(DIN * HID + 255) / 256, 256, 0, stream>>>(W1o, W1po, DIN, HID);
    pack_w_kernel<<<(DIN * HID + 255) / 256, 256, 0, stream>>>(W1i, W1pi, DIN, HID);
    pack_w_kernel<<<(HID * OUTD + 255) / 256, 256, 0, stream>>>(W2o, W2po, HID, OUTD);
    pack_w_kernel<<<(HID * OUTD + 255) / 256, 256, 0, stream>>>(W2i, W2pi, HID, OUTD);

    partition_kernel<<<(E + 255) / 256, 256, 0, stream>>>(ei, E, cnt, list_out, list_in);

    const int nbpb = (E + TE - 1) / TE;
    mlp_scatter_kernel<<<2 * nbpb, 256, 0, stream>>>(
        x, ei, ea, W1po, W1pi, b1o, b1i, W2po, W2pi, b2o, b2i,
        list_out, list_in, cnt, out, E, nbpb);
}

// Round 2
// 694.901 us; speedup vs baseline: 1.6471x; 1.6471x over previous
//
#include <hip/hip_runtime.h>
#include <hip/hip_bf16.h>

typedef __attribute__((ext_vector_type(8))) short short8;
typedef __attribute__((ext_vector_type(4))) float f32x4;

#define DN   128
#define DE   64
#define DIN  192
#define HID  256
#define OUTD 128
#define TE   64      // edges per block
#define MSG_LD 200   // 192 + 8 pad (bf16): row stride 400B -> 4-dword bank shift/row
#define H_LD   264   // 256 + 8 pad: row stride 528B -> 4-dword bank shift/row

static __device__ __forceinline__ unsigned short f2b(float f) {
    unsigned int u = __float_as_uint(f);
    u += 0x7fffu + ((u >> 16) & 1u);
    return (unsigned short)(u >> 16);
}

// One launch packs all four weight matrices to bf16 fragment-ready layout:
// Wp[((k/32)*Ncols + n)*32 + (k%32)]
__global__ void pack_all_kernel(const float* __restrict__ W1o, const float* __restrict__ W1i,
                                const float* __restrict__ W2o, const float* __restrict__ W2i,
                                unsigned short* __restrict__ W1po, unsigned short* __restrict__ W1pi,
                                unsigned short* __restrict__ W2po, unsigned short* __restrict__ W2pi) {
    const int S1 = DIN * HID, S2 = HID * OUTD;
    int idx = blockIdx.x * blockDim.x + threadIdx.x;
    const float* W; unsigned short* Wp; int Ncols, j;
    if      (idx < S1)            { W = W1o; Wp = W1po; Ncols = HID;  j = idx; }
    else if (idx < 2*S1)          { W = W1i; Wp = W1pi; Ncols = HID;  j = idx - S1; }
    else if (idx < 2*S1 + S2)     { W = W2o; Wp = W2po; Ncols = OUTD; j = idx - 2*S1; }
    else if (idx < 2*S1 + 2*S2)   { W = W2i; Wp = W2pi; Ncols = OUTD; j = idx - 2*S1 - S2; }
    else return;
    int k = j / Ncols, n = j - k * Ncols;
    Wp[(((k >> 5) * Ncols + n) << 5) + (k & 31)] = f2b(W[j]);
}

// Partition edges: row<col -> list_out, row>col -> list_in (row==col dropped).
// Block-aggregated: ONE global atomic per block per counter (was per-wave ->
// ~25k same-address serialized RMWs ~ 500us).
__global__ __launch_bounds__(1024)
void partition_kernel(const int* __restrict__ ei, int E,
                      int* __restrict__ cnt,
                      int* __restrict__ list_out, int* __restrict__ list_in) {
    __shared__ int s_wcnt[2][16];
    __shared__ int s_base[2];
    const int tid  = threadIdx.x;
    const int wave = tid >> 6, lane = tid & 63;
    int e = blockIdx.x * blockDim.x + tid;
    bool valid = e < E;
    int r = valid ? ei[e] : 0;
    int c = valid ? ei[E + e] : 0;
    bool po = valid && (r < c);
    bool pi = valid && (r > c);
    unsigned long long mo = __ballot(po);
    unsigned long long mi = __ballot(pi);
    if (lane == 0) { s_wcnt[0][wave] = __popcll(mo); s_wcnt[1][wave] = __popcll(mi); }
    __syncthreads();
    if (tid == 0) {
        int t0 = 0, t1 = 0;
        #pragma unroll
        for (int w = 0; w < 16; ++w) { t0 += s_wcnt[0][w]; t1 += s_wcnt[1][w]; }
        s_base[0] = atomicAdd(&cnt[0], t0);
        s_base[1] = atomicAdd(&cnt[1], t1);
    }
    __syncthreads();
    int woff0 = 0, woff1 = 0;
    for (int w = 0; w < wave; ++w) { woff0 += s_wcnt[0][w]; woff1 += s_wcnt[1][w]; }
    unsigned long long below = (1ull << lane) - 1ull;
    if (po) list_out[s_base[0] + woff0 + __popcll(mo & below)] = e;
    if (pi) list_in [s_base[1] + woff1 + __popcll(mi & below)] = e;
}

__global__ __launch_bounds__(256, 4)
void mlp_scatter_kernel(const float* __restrict__ x,
                        const int* __restrict__ ei,
                        const float* __restrict__ ea,
                        const unsigned short* __restrict__ W1p_out,
                        const unsigned short* __restrict__ W1p_in,
                        const float* __restrict__ b1_out,
                        const float* __restrict__ b1_in,
                        const unsigned short* __restrict__ W2p_out,
                        const unsigned short* __restrict__ W2p_in,
                        const float* __restrict__ b2_out,
                        const float* __restrict__ b2_in,
                        const int* __restrict__ list_out,
                        const int* __restrict__ list_in,
                        const int* __restrict__ cnt,
                        float* __restrict__ out,
                        int E, int nbpb) {
    // Union buffer: msg (TE x MSG_LD = 25600 B) then h (TE x H_LD = 33792 B).
    // GEMM1 accumulators live in registers across the re-use barrier.
    __shared__ __align__(16) unsigned short s_buf[TE * H_LD];
    __shared__ int s_eid[TE], s_dest[TE], s_col[TE];

    const int branch = (blockIdx.x >= nbpb) ? 1 : 0;   // 0 = out-flow, 1 = in-flow
    const int lb = blockIdx.x - branch * nbpb;
    const int count = cnt[branch];
    if (lb * TE >= count) return;
    const int* list            = branch ? list_in : list_out;
    const unsigned short* W1p  = branch ? W1p_in  : W1p_out;
    const float* b1            = branch ? b1_in   : b1_out;
    const unsigned short* W2p  = branch ? W2p_in  : W2p_out;
    const float* b2            = branch ? b2_in   : b2_out;
    const int colbase          = branch ? 0 : OUTD;  // out = concat(flow_in, flow_out)

    const int tid = threadIdx.x;
    if (tid < TE) {
        int idx = lb * TE + tid;
        int e = (idx < count) ? list[idx] : -1;
        s_eid[tid]  = e;
        s_dest[tid] = (e >= 0) ? ei[e] : -1;       // row = scatter dest
        s_col[tid]  = (e >= 0) ? ei[E + e] : 0;    // col = gather src
    }
    __syncthreads();

    // Gather msg = concat(x[col], edge_attr[e]) as bf16 into LDS.
    // 4 threads per edge, 12 independent float4 loads each (unrolled for ILP).
    {
        const int le  = tid >> 2;
        const int sub = tid & 3;
        const int e   = s_eid[le];
        const long xbase = (long)s_col[le] * 32;
        const long ebase = (long)e * 16;
        #pragma unroll
        for (int j = 0; j < 12; ++j) {
            int q = sub + j * 4;
            float4 v = make_float4(0.f, 0.f, 0.f, 0.f);
            if (e >= 0) {
                if (j < 8) v = reinterpret_cast<const float4*>(x)[xbase + q];
                else       v = reinterpret_cast<const float4*>(ea)[ebase + (q - 32)];
            }
            unsigned int lo = (unsigned int)f2b(v.x) | ((unsigned int)f2b(v.y) << 16);
            unsigned int hi = (unsigned int)f2b(v.z) | ((unsigned int)f2b(v.w) << 16);
            *reinterpret_cast<uint2*>(&s_buf[le * MSG_LD + q * 4]) = make_uint2(lo, hi);
        }
    }
    __syncthreads();

    const int wave = tid >> 6;
    const int lane = tid & 63;
    const int ln   = lane & 15;
    const int quad = lane >> 4;

    // ---- GEMM1: h = relu(msg @ W1 + b1).  M=64, N=256 (64/wave), K=192.
    f32x4 acc[4][4];
    {
        const int nbase = wave * 64;
        float bias[4];
        #pragma unroll
        for (int t = 0; t < 4; ++t) bias[t] = b1[nbase + t * 16 + ln];
        #pragma unroll
        for (int mt = 0; mt < 4; ++mt)
            #pragma unroll
            for (int t = 0; t < 4; ++t)
                acc[mt][t] = (f32x4){bias[t], bias[t], bias[t], bias[t]};
        #pragma unroll
        for (int kt = 0; kt < DIN / 32; ++kt) {
            short8 a[4], b[4];
            #pragma unroll
            for (int mt = 0; mt < 4; ++mt)
                a[mt] = *reinterpret_cast<const short8*>(
                    &s_buf[(mt * 16 + ln) * MSG_LD + kt * 32 + quad * 8]);
            #pragma unroll
            for (int t = 0; t < 4; ++t)
                b[t] = *reinterpret_cast<const short8*>(
                    &W1p[((kt * HID + nbase + t * 16 + ln) << 5) + quad * 8]);
            #pragma unroll
            for (int mt = 0; mt < 4; ++mt)
                #pragma unroll
                for (int t = 0; t < 4; ++t)
                    acc[mt][t] = __builtin_amdgcn_mfma_f32_16x16x32_bf16(a[mt], b[t], acc[mt][t], 0, 0, 0);
        }
    }
    __syncthreads();   // all waves done READING msg; s_buf can be re-used for h

    // ReLU -> bf16 h into s_buf (stride H_LD). C/D map: col=lane&15, row=quad*4+reg.
    {
        const int nbase = wave * 64;
        #pragma unroll
        for (int mt = 0; mt < 4; ++mt)
            #pragma unroll
            for (int t = 0; t < 4; ++t) {
                int ncol = nbase + t * 16 + ln;
                #pragma unroll
                for (int r = 0; r < 4; ++r) {
                    int m = mt * 16 + quad * 4 + r;
                    float v = acc[mt][t][r];
                    s_buf[m * H_LD + ncol] = f2b(v > 0.f ? v : 0.f);
                }
            }
    }
    __syncthreads();

    // ---- GEMM2: o = h @ W2 + b2.  M=64, N=128 (32/wave), K=256. Scatter-add by row.
    {
        const int nbase = wave * 32;
        float bias2[2];
        #pragma unroll
        for (int t = 0; t < 2; ++t) bias2[t] = b2[nbase + t * 16 + ln];
        f32x4 acc2[4][2];
        #pragma unroll
        for (int mt = 0; mt < 4; ++mt)
            #pragma unroll
            for (int t = 0; t < 2; ++t)
                acc2[mt][t] = (f32x4){bias2[t], bias2[t], bias2[t], bias2[t]};
        #pragma unroll
        for (int kt = 0; kt < HID / 32; ++kt) {
            short8 a[4], b[2];
            #pragma unroll
            for (int mt = 0; mt < 4; ++mt)
                a[mt] = *reinterpret_cast<const short8*>(
                    &s_buf[(mt * 16 + ln) * H_LD + kt * 32 + quad * 8]);
            #pragma unroll
            for (int t = 0; t < 2; ++t)
                b[t] = *reinterpret_cast<const short8*>(
                    &W2p[((kt * OUTD + nbase + t * 16 + ln) << 5) + quad * 8]);
            #pragma unroll
            for (int mt = 0; mt < 4; ++mt)
                #pragma unroll
                for (int t = 0; t < 2; ++t)
                    acc2[mt][t] = __builtin_amdgcn_mfma_f32_16x16x32_bf16(a[mt], b[t], acc2[mt][t], 0, 0, 0);
        }
        #pragma unroll
        for (int mt = 0; mt < 4; ++mt) {
            #pragma unroll
            for (int r = 0; r < 4; ++r) {
                int m = mt * 16 + quad * 4 + r;
                int dest = s_dest[m];
                if (dest >= 0) {
                    float* orow = out + (size_t)dest * (2 * OUTD) + colbase + nbase + ln;
                    atomicAdd(orow,      acc2[mt][0][r]);
                    atomicAdd(orow + 16, acc2[mt][1][r]);
                }
            }
        }
    }
}

extern "C" void kernel_launch(void* const* d_in, const int* in_sizes, int n_in,
                              void* d_out, int out_size, void* d_ws, size_t ws_size,
                              hipStream_t stream) {
    const float* x   = (const float*)d_in[0];
    const int*   ei  = (const int*)d_in[1];
    const float* ea  = (const float*)d_in[2];
    const float* W1o = (const float*)d_in[3];
    const float* b1o = (const float*)d_in[4];
    const float* W2o = (const float*)d_in[5];
    const float* b2o = (const float*)d_in[6];
    const float* W1i = (const float*)d_in[7];
    const float* b1i = (const float*)d_in[8];
    const float* W2i = (const float*)d_in[9];
    const float* b2i = (const float*)d_in[10];
    float* out = (float*)d_out;
    const int E = in_sizes[1] / 2;

    char* ws = (char*)d_ws;
    int* cnt      = (int*)ws;                                  // 2 counters
    int* list_out = (int*)(ws + 256);
    int* list_in  = list_out + E;
    unsigned short* W1po = (unsigned short*)(ws + 256 + (size_t)2 * E * sizeof(int));
    unsigned short* W1pi = W1po + DIN * HID;
    unsigned short* W2po = W1pi + DIN * HID;
    unsigned short* W2pi = W2po + HID * OUTD;

    hipMemsetAsync(d_out, 0, (size_t)out_size * sizeof(float), stream);
    hipMemsetAsync(cnt, 0, 2 * sizeof(int), stream);

    const int packN = 2 * DIN * HID + 2 * HID * OUTD;
    pack_all_kernel<<<(packN + 255) / 256, 256, 0, stream>>>(
        W1o, W1i, W2o, W2i, W1po, W1pi, W2po, W2pi);

    partition_kernel<<<(E + 1023) / 1024, 1024, 0, stream>>>(ei, E, cnt, list_out, list_in);

    const int nbpb = (E + TE - 1) / TE;
    mlp_scatter_kernel<<<2 * nbpb, 256, 0, stream>>>(
        x, ei, ea, W1po, W1pi, b1o, b1i, W2po, W2pi, b2o, b2i,
        list_out, list_in, cnt, out, E, nbpb);
}

// Round 3
// 660.372 us; speedup vs baseline: 1.7332x; 1.0523x over previous
//
#include <hip/hip_runtime.h>
#include <hip/hip_bf16.h>

typedef __attribute__((ext_vector_type(8))) short short8;
typedef __attribute__((ext_vector_type(4))) float f32x4;

#define DN   128
#define DE   64
#define DIN  192
#define HID  256
#define OUTD 128
#define TE   64      // edges per block
#define MSG_LD 200   // 192 + 8 pad (bf16): row stride 400B -> 4-dword bank shift/row
#define H_LD   264   // 256 + 8 pad (bf16): row stride 528B -> 4-dword bank shift/row
#define OUT_LD 132   // f32 out tile stride (128 + 4): row stride 528B, same shift

static __device__ __forceinline__ unsigned short f2b(float f) {
    unsigned int u = __float_as_uint(f);
    u += 0x7fffu + ((u >> 16) & 1u);
    return (unsigned short)(u >> 16);
}

// One launch packs all four weight matrices to bf16 fragment-ready layout:
// Wp[((k/32)*Ncols + n)*32 + (k%32)]
__global__ void pack_all_kernel(const float* __restrict__ W1o, const float* __restrict__ W1i,
                                const float* __restrict__ W2o, const float* __restrict__ W2i,
                                unsigned short* __restrict__ W1po, unsigned short* __restrict__ W1pi,
                                unsigned short* __restrict__ W2po, unsigned short* __restrict__ W2pi) {
    const int S1 = DIN * HID, S2 = HID * OUTD;
    int idx = blockIdx.x * blockDim.x + threadIdx.x;
    const float* W; unsigned short* Wp; int Ncols, j;
    if      (idx < S1)            { W = W1o; Wp = W1po; Ncols = HID;  j = idx; }
    else if (idx < 2*S1)          { W = W1i; Wp = W1pi; Ncols = HID;  j = idx - S1; }
    else if (idx < 2*S1 + S2)     { W = W2o; Wp = W2po; Ncols = OUTD; j = idx - 2*S1; }
    else if (idx < 2*S1 + 2*S2)   { W = W2i; Wp = W2pi; Ncols = OUTD; j = idx - 2*S1 - S2; }
    else return;
    int k = j / Ncols, n = j - k * Ncols;
    Wp[(((k >> 5) * Ncols + n) << 5) + (k & 31)] = f2b(W[j]);
}

// Per-branch histogram of destination rows. hist[0..N) = out-branch, hist[N..2N) = in.
__global__ __launch_bounds__(256)
void part_hist_kernel(const int* __restrict__ ei, int E, int N, int* __restrict__ hist) {
    int e = blockIdx.x * blockDim.x + threadIdx.x;
    if (e >= E) return;
    int r = ei[e], c = ei[E + e];
    if      (r < c) atomicAdd(&hist[r], 1);
    else if (r > c) atomicAdd(&hist[N + r], 1);
}

// Exclusive scan of one branch's histogram -> cursor (start offsets); cnt[b] = total.
// One block per branch, wave-shuffle scan (2-3 barriers per 1024-chunk).
__global__ __launch_bounds__(1024)
void scan_kernel(const int* __restrict__ hist, int* __restrict__ cursor,
                 int* __restrict__ cnt, int N) {
    __shared__ int s_ws[16];
    __shared__ int s_run;
    const int tid = threadIdx.x, lane = tid & 63, wv = tid >> 6;
    const int b = blockIdx.x;
    const int* h = hist + (size_t)b * N;
    int* cu = cursor + (size_t)b * N;
    if (tid == 0) s_run = 0;
    __syncthreads();
    for (int base = 0; base < N; base += 1024) {
        int i = base + tid;
        int v = (i < N) ? h[i] : 0;
        int incl = v;
        #pragma unroll
        for (int d = 1; d < 64; d <<= 1) {
            int t = __shfl_up(incl, d, 64);
            if (lane >= d) incl += t;
        }
        if (lane == 63) s_ws[wv] = incl;
        __syncthreads();
        if (tid < 16) {
            int w = s_ws[tid];
            int wi = w;
            #pragma unroll
            for (int d = 1; d < 16; d <<= 1) {
                int t = __shfl_up(wi, d, 64);
                if (tid >= d) wi += t;
            }
            s_ws[tid] = wi - w;   // exclusive wave offset
        }
        __syncthreads();
        int excl = s_run + s_ws[wv] + incl - v;
        if (i < N) cu[i] = excl;
        __syncthreads();                       // all reads of s_run done
        if (tid == 1023) s_run = excl + v;     // running total
        __syncthreads();
    }
    if (tid == 0) cnt[b] = s_run;
}

// Scatter each edge to its sorted-by-dest-row position (within-row order arbitrary).
__global__ __launch_bounds__(256)
void reorder_kernel(const int* __restrict__ ei, int E, int N, int* __restrict__ cursor,
                    int* __restrict__ list_out, int* __restrict__ list_in) {
    int e = blockIdx.x * blockDim.x + threadIdx.x;
    if (e >= E) return;
    int r = ei[e], c = ei[E + e];
    if      (r < c) { int p = atomicAdd(&cursor[r], 1);            list_out[p] = e; }
    else if (r > c) { int p = atomicAdd(&cursor[(size_t)N + r], 1); list_in[p] = e; }
}

__global__ __launch_bounds__(256, 4)
void mlp_scatter_kernel(const float* __restrict__ x,
                        const int* __restrict__ ei,
                        const float* __restrict__ ea,
                        const unsigned short* __restrict__ W1p_out,
                        const unsigned short* __restrict__ W1p_in,
                        const float* __restrict__ b1_out,
                        const float* __restrict__ b1_in,
                        const unsigned short* __restrict__ W2p_out,
                        const unsigned short* __restrict__ W2p_in,
                        const float* __restrict__ b2_out,
                        const float* __restrict__ b2_in,
                        const int* __restrict__ list_out,
                        const int* __restrict__ list_in,
                        const int* __restrict__ cnt,
                        float* __restrict__ out,
                        int E, int nbpb) {
    // Union buffer, 33792 B: msg bf16 (64 x 200) -> h bf16 (64 x 264) -> out f32 (64 x 132).
    __shared__ __align__(16) unsigned short s_buf[TE * H_LD];
    __shared__ int s_eid[TE], s_dest[TE], s_col[TE];

    const int branch = (blockIdx.x >= nbpb) ? 1 : 0;   // 0 = out-flow, 1 = in-flow
    const int lb = blockIdx.x - branch * nbpb;
    const int count = cnt[branch];
    if (lb * TE >= count) return;
    const int* list            = branch ? list_in : list_out;
    const unsigned short* W1p  = branch ? W1p_in  : W1p_out;
    const float* b1            = branch ? b1_in   : b1_out;
    const unsigned short* W2p  = branch ? W2p_in  : W2p_out;
    const float* b2            = branch ? b2_in   : b2_out;
    const int colbase          = branch ? 0 : OUTD;  // out = concat(flow_in, flow_out)

    const int tid = threadIdx.x;
    if (tid < TE) {
        int idx = lb * TE + tid;
        int e = (idx < count) ? list[idx] : -1;
        s_eid[tid]  = e;
        s_dest[tid] = (e >= 0) ? ei[e] : -1;       // row = scatter dest (sorted, non-decreasing)
        s_col[tid]  = (e >= 0) ? ei[E + e] : 0;    // col = gather src
    }
    __syncthreads();

    // Gather msg = concat(x[col], edge_attr[e]) as bf16 into LDS.
    {
        const int le  = tid >> 2;
        const int sub = tid & 3;
        const int e   = s_eid[le];
        const long xbase = (long)s_col[le] * 32;
        const long ebase = (long)e * 16;
        #pragma unroll
        for (int j = 0; j < 12; ++j) {
            int q = sub + j * 4;
            float4 v = make_float4(0.f, 0.f, 0.f, 0.f);
            if (e >= 0) {
                if (j < 8) v = reinterpret_cast<const float4*>(x)[xbase + q];
                else       v = reinterpret_cast<const float4*>(ea)[ebase + (q - 32)];
            }
            unsigned int lo = (unsigned int)f2b(v.x) | ((unsigned int)f2b(v.y) << 16);
            unsigned int hi = (unsigned int)f2b(v.z) | ((unsigned int)f2b(v.w) << 16);
            *reinterpret_cast<uint2*>(&s_buf[le * MSG_LD + q * 4]) = make_uint2(lo, hi);
        }
    }
    __syncthreads();

    const int wave = tid >> 6;
    const int lane = tid & 63;
    const int ln   = lane & 15;
    const int quad = lane >> 4;

    // ---- GEMM1: h = relu(msg @ W1 + b1).  M=64, N=256 (64/wave), K=192.
    f32x4 acc[4][4];
    {
        const int nbase = wave * 64;
        float bias[4];
        #pragma unroll
        for (int t = 0; t < 4; ++t) bias[t] = b1[nbase + t * 16 + ln];
        #pragma unroll
        for (int mt = 0; mt < 4; ++mt)
            #pragma unroll
            for (int t = 0; t < 4; ++t)
                acc[mt][t] = (f32x4){bias[t], bias[t], bias[t], bias[t]};
        #pragma unroll
        for (int kt = 0; kt < DIN / 32; ++kt) {
            short8 a[4], b[4];
            #pragma unroll
            for (int mt = 0; mt < 4; ++mt)
                a[mt] = *reinterpret_cast<const short8*>(
                    &s_buf[(mt * 16 + ln) * MSG_LD + kt * 32 + quad * 8]);
            #pragma unroll
            for (int t = 0; t < 4; ++t)
                b[t] = *reinterpret_cast<const short8*>(
                    &W1p[((kt * HID + nbase + t * 16 + ln) << 5) + quad * 8]);
            #pragma unroll
            for (int mt = 0; mt < 4; ++mt)
                #pragma unroll
                for (int t = 0; t < 4; ++t)
                    acc[mt][t] = __builtin_amdgcn_mfma_f32_16x16x32_bf16(a[mt], b[t], acc[mt][t], 0, 0, 0);
        }
    }
    __syncthreads();   // all waves done READING msg; s_buf re-used for h

    // ReLU -> bf16 h into s_buf (stride H_LD). C/D map: col=lane&15, row=quad*4+reg.
    {
        const int nbase = wave * 64;
        #pragma unroll
        for (int mt = 0; mt < 4; ++mt)
            #pragma unroll
            for (int t = 0; t < 4; ++t) {
                int ncol = nbase + t * 16 + ln;
                #pragma unroll
                for (int r = 0; r < 4; ++r) {
                    int m = mt * 16 + quad * 4 + r;
                    float v = acc[mt][t][r];
                    s_buf[m * H_LD + ncol] = f2b(v > 0.f ? v : 0.f);
                }
            }
    }
    __syncthreads();

    // ---- GEMM2: o = h @ W2 + b2.  M=64, N=128 (32/wave), K=256.
    f32x4 acc2[4][2];
    {
        const int nbase = wave * 32;
        float bias2[2];
        #pragma unroll
        for (int t = 0; t < 2; ++t) bias2[t] = b2[nbase + t * 16 + ln];
        #pragma unroll
        for (int mt = 0; mt < 4; ++mt)
            #pragma unroll
            for (int t = 0; t < 2; ++t)
                acc2[mt][t] = (f32x4){bias2[t], bias2[t], bias2[t], bias2[t]};
        #pragma unroll
        for (int kt = 0; kt < HID / 32; ++kt) {
            short8 a[4], b[2];
            #pragma unroll
            for (int mt = 0; mt < 4; ++mt)
                a[mt] = *reinterpret_cast<const short8*>(
                    &s_buf[(mt * 16 + ln) * H_LD + kt * 32 + quad * 8]);
            #pragma unroll
            for (int t = 0; t < 2; ++t)
                b[t] = *reinterpret_cast<const short8*>(
                    &W2p[((kt * OUTD + nbase + t * 16 + ln) << 5) + quad * 8]);
            #pragma unroll
            for (int mt = 0; mt < 4; ++mt)
                #pragma unroll
                for (int t = 0; t < 2; ++t)
                    acc2[mt][t] = __builtin_amdgcn_mfma_f32_16x16x32_bf16(a[mt], b[t], acc2[mt][t], 0, 0, 0);
        }
    }
    __syncthreads();   // all waves done READING h; s_buf re-used for f32 out tile

    // Spill GEMM2 results to LDS as f32 (64 x OUT_LD).
    float* s_outf = reinterpret_cast<float*>(s_buf);
    {
        const int nbase = wave * 32;
        #pragma unroll
        for (int mt = 0; mt < 4; ++mt)
            #pragma unroll
            for (int t = 0; t < 2; ++t)
                #pragma unroll
                for (int r = 0; r < 4; ++r)
                    s_outf[(mt * 16 + quad * 4 + r) * OUT_LD + nbase + t * 16 + ln] = acc2[mt][t][r];
    }
    __syncthreads();

    // Segment-reduce over sorted dest rows: one atomic per (run, column).
    // thread -> column (tid & 127) x row-half (tid >> 7).
    {
        const int c  = tid & 127;
        const int m0 = (tid >> 7) * 32;
        float run = 0.f;
        int cur = -1;
        #pragma unroll 8
        for (int m = m0; m < m0 + 32; ++m) {
            int d = s_dest[m];
            float v = s_outf[m * OUT_LD + c];
            if (d != cur) {
                if (cur >= 0) atomicAdd(&out[(size_t)cur * (2 * OUTD) + colbase + c], run);
                cur = d; run = 0.f;
            }
            if (d >= 0) run += v;
        }
        if (cur >= 0) atomicAdd(&out[(size_t)cur * (2 * OUTD) + colbase + c], run);
    }
}

extern "C" void kernel_launch(void* const* d_in, const int* in_sizes, int n_in,
                              void* d_out, int out_size, void* d_ws, size_t ws_size,
                              hipStream_t stream) {
    const float* x   = (const float*)d_in[0];
    const int*   ei  = (const int*)d_in[1];
    const float* ea  = (const float*)d_in[2];
    const float* W1o = (const float*)d_in[3];
    const float* b1o = (const float*)d_in[4];
    const float* W2o = (const float*)d_in[5];
    const float* b2o = (const float*)d_in[6];
    const float* W1i = (const float*)d_in[7];
    const float* b1i = (const float*)d_in[8];
    const float* W2i = (const float*)d_in[9];
    const float* b2i = (const float*)d_in[10];
    float* out = (float*)d_out;
    const int E = in_sizes[1] / 2;
    const int N = in_sizes[0] / DN;

    // workspace layout
    char* ws = (char*)d_ws;
    int* cnt      = (int*)ws;                 // [0,64): 2 counters (+pad)
    int* hist     = (int*)(ws + 64);          // 2N ints
    int* cursor   = hist + 2 * (size_t)N;     // 2N ints
    int* list_out = cursor + 2 * (size_t)N;   // E ints (sorted by dest row)
    int* list_in  = list_out + E;             // E ints
    unsigned short* W1po = (unsigned short*)(list_in + E);
    unsigned short* W1pi = W1po + DIN * HID;
    unsigned short* W2po = W1pi + DIN * HID;
    unsigned short* W2pi = W2po + HID * OUTD;

    hipMemsetAsync(d_out, 0, (size_t)out_size * sizeof(float), stream);
    hipMemsetAsync(ws, 0, 64 + 2 * (size_t)N * sizeof(int), stream);   // cnt + hist

    const int packN = 2 * DIN * HID + 2 * HID * OUTD;
    pack_all_kernel<<<(packN + 255) / 256, 256, 0, stream>>>(
        W1o, W1i, W2o, W2i, W1po, W1pi, W2po, W2pi);

    part_hist_kernel<<<(E + 255) / 256, 256, 0, stream>>>(ei, E, N, hist);
    scan_kernel<<<2, 1024, 0, stream>>>(hist, cursor, cnt, N);
    reorder_kernel<<<(E + 255) / 256, 256, 0, stream>>>(ei, E, N, cursor, list_out, list_in);

    const int nbpb = (E + TE - 1) / TE;
    mlp_scatter_kernel<<<2 * nbpb, 256, 0, stream>>>(
        x, ei, ea, W1po, W1pi, b1o, b1i, W2po, W2pi, b2o, b2i,
        list_out, list_in, cnt, out, E, nbpb);
}

// Round 4
// 603.502 us; speedup vs baseline: 1.8965x; 1.0942x over previous
//
#include <hip/hip_runtime.h>
#include <hip/hip_bf16.h>

typedef __attribute__((ext_vector_type(8))) short short8;
typedef __attribute__((ext_vector_type(8))) unsigned short ushort8;
typedef __attribute__((ext_vector_type(4))) float f32x4;

#define DN   128
#define DE   64
#define DIN  192
#define HID  256
#define OUTD 128
#define TE   64      // edges per block
#define MSG_LD 200   // 192 + 8 pad (bf16): row stride 400B -> 4-dword bank shift/row
#define H_LD   264   // 256 + 8 pad (bf16): row stride 528B -> 4-dword bank shift/row
#define OUT_LD 132   // f32 out tile stride (128 + 4)

static __device__ __forceinline__ unsigned short f2b(float f) {
    unsigned int u = __float_as_uint(f);
    u += 0x7fffu + ((u >> 16) & 1u);
    return (unsigned short)(u >> 16);
}

// Fused prep: (a) pack 4 weight mats to bf16 fragment layout Wp[((k/32)*Nc+n)*32+(k%32)],
// (b) histogram dest rows per branch, (c) convert x to bf16.
__global__ __launch_bounds__(256)
void prep_kernel(const float* __restrict__ W1o, const float* __restrict__ W1i,
                 const float* __restrict__ W2o, const float* __restrict__ W2i,
                 unsigned short* __restrict__ W1po, unsigned short* __restrict__ W1pi,
                 unsigned short* __restrict__ W2po, unsigned short* __restrict__ W2pi,
                 const int* __restrict__ ei, int E, int N, int* __restrict__ hist,
                 const float* __restrict__ x, unsigned short* __restrict__ xb) {
    const int S1 = DIN * HID, S2v = HID * OUTD;
    const int PACKN = 2 * S1 + 2 * S2v;
    int idx = blockIdx.x * blockDim.x + threadIdx.x;
    if (idx < PACKN) {
        const float* W; unsigned short* Wp; int Nc, j;
        if      (idx < S1)          { W = W1o; Wp = W1po; Nc = HID;  j = idx; }
        else if (idx < 2*S1)        { W = W1i; Wp = W1pi; Nc = HID;  j = idx - S1; }
        else if (idx < 2*S1 + S2v)  { W = W2o; Wp = W2po; Nc = OUTD; j = idx - 2*S1; }
        else                        { W = W2i; Wp = W2pi; Nc = OUTD; j = idx - 2*S1 - S2v; }
        int k = j / Nc, n = j - k * Nc;
        Wp[(((k >> 5) * Nc + n) << 5) + (k & 31)] = f2b(W[j]);
    } else if (idx < PACKN + E) {
        int e = idx - PACKN;
        int r = ei[e], c = ei[E + e];
        if      (r < c) atomicAdd(&hist[r], 1);
        else if (r > c) atomicAdd(&hist[N + r], 1);
    } else {
        int i = idx - PACKN - E;           // 8 x-floats per thread
        if (i < N * DN / 8) {
            float4 a = reinterpret_cast<const float4*>(x)[i * 2];
            float4 b = reinterpret_cast<const float4*>(x)[i * 2 + 1];
            ushort8 v = { f2b(a.x), f2b(a.y), f2b(a.z), f2b(a.w),
                          f2b(b.x), f2b(b.y), f2b(b.z), f2b(b.w) };
            reinterpret_cast<ushort8*>(xb)[i] = v;
        }
    }
}

// Per-chunk (1024 rows) exclusive scan of one branch's histogram.
// cursor[i] = within-chunk exclusive prefix; chunkSum[br*nch+ch] = chunk total.
__global__ __launch_bounds__(1024)
void scan1_kernel(const int* __restrict__ hist, int* __restrict__ cursor,
                  int* __restrict__ chunkSum, int N, int nch) {
    __shared__ int s_ws[16];
    const int br = blockIdx.x / nch, ch = blockIdx.x - br * nch;
    const int tid = threadIdx.x, lane = tid & 63, wv = tid >> 6;
    const int i = ch * 1024 + tid;
    int v = (i < N) ? hist[(size_t)br * N + i] : 0;
    int incl = v;
    #pragma unroll
    for (int d = 1; d < 64; d <<= 1) {
        int t = __shfl_up(incl, d, 64);
        if (lane >= d) incl += t;
    }
    if (lane == 63) s_ws[wv] = incl;
    __syncthreads();
    if (tid < 16) {
        int w = s_ws[tid];
        int wi = w;
        #pragma unroll
        for (int d = 1; d < 16; d <<= 1) {
            int t = __shfl_up(wi, d, 64);
            if (tid >= d) wi += t;
        }
        s_ws[tid] = wi - w;
    }
    __syncthreads();
    int excl = s_ws[wv] + incl - v;
    if (i < N) cursor[(size_t)br * N + i] = excl;
    if (tid == 1023) chunkSum[br * nch + ch] = excl + v;
}

// Scan chunk sums (nch <= 64 per branch): wave 0 -> branch 0, wave 1 -> branch 1.
// In-place: chunkSum becomes exclusive chunk base; cnt[br] = branch total.
__global__ __launch_bounds__(128)
void scan2_kernel(int* __restrict__ chunkSum, int* __restrict__ cnt, int nch) {
    const int br = threadIdx.x >> 6, lane = threadIdx.x & 63;
    int v = (lane < nch) ? chunkSum[br * nch + lane] : 0;
    int incl = v;
    #pragma unroll
    for (int d = 1; d < 64; d <<= 1) {
        int t = __shfl_up(incl, d, 64);
        if (lane >= d) incl += t;
    }
    if (lane < nch) chunkSum[br * nch + lane] = incl - v;
    if (lane == nch - 1) cnt[br] = incl;
}

// Scatter edges to sorted-by-dest-row positions.
__global__ __launch_bounds__(256)
void reorder_kernel(const int* __restrict__ ei, int E, int N, int nch,
                    int* __restrict__ cursor, const int* __restrict__ chunkSum,
                    int* __restrict__ list_out, int* __restrict__ list_in) {
    int e = blockIdx.x * blockDim.x + threadIdx.x;
    if (e >= E) return;
    int r = ei[e], c = ei[E + e];
    if (r == c) return;
    int br = (r < c) ? 0 : 1;
    int p = chunkSum[br * nch + (r >> 10)] + atomicAdd(&cursor[(size_t)br * N + r], 1);
    (br ? list_in : list_out)[p] = e;
}

__global__ __launch_bounds__(256, 4)
void mlp_scatter_kernel(const unsigned short* __restrict__ xb,
                        const int* __restrict__ ei,
                        const float* __restrict__ ea,
                        const unsigned short* __restrict__ W1p_out,
                        const unsigned short* __restrict__ W1p_in,
                        const float* __restrict__ b1_out,
                        const float* __restrict__ b1_in,
                        const unsigned short* __restrict__ W2p_out,
                        const unsigned short* __restrict__ W2p_in,
                        const float* __restrict__ b2_out,
                        const float* __restrict__ b2_in,
                        const int* __restrict__ list_out,
                        const int* __restrict__ list_in,
                        const int* __restrict__ cnt,
                        float* __restrict__ out,
                        int E, int nbpb) {
    // Union buffer, 33792 B: msg bf16 (64x200) -> h bf16 (64x264) -> out f32 (64x132).
    __shared__ __align__(16) unsigned short s_buf[TE * H_LD];
    __shared__ int s_eid[TE], s_dest[TE], s_col[TE];

    const int branch = (blockIdx.x >= nbpb) ? 1 : 0;   // 0 = out-flow, 1 = in-flow
    const int lb = blockIdx.x - branch * nbpb;
    const int count = cnt[branch];
    if (lb * TE >= count) return;
    const int* list            = branch ? list_in : list_out;
    const unsigned short* W1p  = branch ? W1p_in  : W1p_out;
    const float* b1            = branch ? b1_in   : b1_out;
    const unsigned short* W2p  = branch ? W2p_in  : W2p_out;
    const float* b2            = branch ? b2_in   : b2_out;
    const int colbase          = branch ? 0 : OUTD;  // out = concat(flow_in, flow_out)

    const int tid = threadIdx.x;
    if (tid < TE) {
        int idx = lb * TE + tid;
        int e = (idx < count) ? list[idx] : -1;
        s_eid[tid]  = e;
        s_dest[tid] = (e >= 0) ? ei[e] : -1;       // sorted non-decreasing dest rows
        s_col[tid]  = (e >= 0) ? ei[E + e] : 0;
    }
    __syncthreads();

    // Gather msg = concat(xb[col] (bf16), f2b(edge_attr[e])) into LDS. 4 threads/edge.
    {
        const int le  = tid >> 2;
        const int sub = tid & 3;
        const int e   = s_eid[le];
        const ushort8* xrow = reinterpret_cast<const ushort8*>(xb) + (size_t)s_col[le] * (DN / 8);
        #pragma unroll
        for (int j = 0; j < 4; ++j) {
            int seg = sub + j * 4;                       // elems [seg*8, seg*8+8)
            ushort8 v = {0, 0, 0, 0, 0, 0, 0, 0};
            if (e >= 0) v = xrow[seg];
            *reinterpret_cast<ushort8*>(&s_buf[le * MSG_LD + seg * 8]) = v;
        }
        const float4* erow = reinterpret_cast<const float4*>(ea) + (size_t)e * (DE / 4);
        #pragma unroll
        for (int j = 0; j < 4; ++j) {
            float4 v = make_float4(0.f, 0.f, 0.f, 0.f);
            if (e >= 0) v = erow[sub * 4 + j];
            unsigned int lo = (unsigned int)f2b(v.x) | ((unsigned int)f2b(v.y) << 16);
            unsigned int hi = (unsigned int)f2b(v.z) | ((unsigned int)f2b(v.w) << 16);
            *reinterpret_cast<uint2*>(&s_buf[le * MSG_LD + DN + sub * 16 + j * 4]) = make_uint2(lo, hi);
        }
    }
    __syncthreads();

    const int wave = tid >> 6;
    const int lane = tid & 63;
    const int ln   = lane & 15;
    const int quad = lane >> 4;

    // ---- GEMM1: h = relu(msg @ W1 + b1).  M=64, N=256 (64/wave), K=192.
    f32x4 acc[4][4];
    {
        const int nbase = wave * 64;
        float bias[4];
        #pragma unroll
        for (int t = 0; t < 4; ++t) bias[t] = b1[nbase + t * 16 + ln];
        #pragma unroll
        for (int mt = 0; mt < 4; ++mt)
            #pragma unroll
            for (int t = 0; t < 4; ++t)
                acc[mt][t] = (f32x4){bias[t], bias[t], bias[t], bias[t]};
        #pragma unroll
        for (int kt = 0; kt < DIN / 32; ++kt) {
            short8 a[4], b[4];
            #pragma unroll
            for (int mt = 0; mt < 4; ++mt)
                a[mt] = *reinterpret_cast<const short8*>(
                    &s_buf[(mt * 16 + ln) * MSG_LD + kt * 32 + quad * 8]);
            #pragma unroll
            for (int t = 0; t < 4; ++t)
                b[t] = *reinterpret_cast<const short8*>(
                    &W1p[((kt * HID + nbase + t * 16 + ln) << 5) + quad * 8]);
            #pragma unroll
            for (int mt = 0; mt < 4; ++mt)
                #pragma unroll
                for (int t = 0; t < 4; ++t)
                    acc[mt][t] = __builtin_amdgcn_mfma_f32_16x16x32_bf16(a[mt], b[t], acc[mt][t], 0, 0, 0);
        }
    }
    __syncthreads();   // msg reads done; s_buf re-used for h

    // ReLU -> bf16 h into s_buf (stride H_LD). C/D map: col=lane&15, row=quad*4+reg.
    {
        const int nbase = wave * 64;
        #pragma unroll
        for (int mt = 0; mt < 4; ++mt)
            #pragma unroll
            for (int t = 0; t < 4; ++t) {
                int ncol = nbase + t * 16 + ln;
                #pragma unroll
                for (int r = 0; r < 4; ++r) {
                    int m = mt * 16 + quad * 4 + r;
                    float v = acc[mt][t][r];
                    s_buf[m * H_LD + ncol] = f2b(v > 0.f ? v : 0.f);
                }
            }
    }
    __syncthreads();

    // ---- GEMM2: o = h @ W2 + b2.  M=64, N=128 (32/wave), K=256.
    f32x4 acc2[4][2];
    {
        const int nbase = wave * 32;
        float bias2[2];
        #pragma unroll
        for (int t = 0; t < 2; ++t) bias2[t] = b2[nbase + t * 16 + ln];
        #pragma unroll
        for (int mt = 0; mt < 4; ++mt)
            #pragma unroll
            for (int t = 0; t < 2; ++t)
                acc2[mt][t] = (f32x4){bias2[t], bias2[t], bias2[t], bias2[t]};
        #pragma unroll
        for (int kt = 0; kt < HID / 32; ++kt) {
            short8 a[4], b[2];
            #pragma unroll
            for (int mt = 0; mt < 4; ++mt)
                a[mt] = *reinterpret_cast<const short8*>(
                    &s_buf[(mt * 16 + ln) * H_LD + kt * 32 + quad * 8]);
            #pragma unroll
            for (int t = 0; t < 2; ++t)
                b[t] = *reinterpret_cast<const short8*>(
                    &W2p[((kt * OUTD + nbase + t * 16 + ln) << 5) + quad * 8]);
            #pragma unroll
            for (int mt = 0; mt < 4; ++mt)
                #pragma unroll
                for (int t = 0; t < 2; ++t)
                    acc2[mt][t] = __builtin_amdgcn_mfma_f32_16x16x32_bf16(a[mt], b[t], acc2[mt][t], 0, 0, 0);
        }
    }
    __syncthreads();   // h reads done; s_buf re-used for f32 out tile

    float* s_outf = reinterpret_cast<float*>(s_buf);
    {
        const int nbase = wave * 32;
        #pragma unroll
        for (int mt = 0; mt < 4; ++mt)
            #pragma unroll
            for (int t = 0; t < 2; ++t)
                #pragma unroll
                for (int r = 0; r < 4; ++r)
                    s_outf[(mt * 16 + quad * 4 + r) * OUT_LD + nbase + t * 16 + ln] = acc2[mt][t][r];
    }
    __syncthreads();

    // Segment-reduce over sorted dest rows. Runs strictly interior to this
    // thread's row-range are sole-owner -> plain store; boundary runs -> atomic.
    {
        const int c  = tid & 127;
        const int m0 = (tid >> 7) * 32;
        float run = 0.f;
        int cur = -1, rs = m0;
        for (int m = m0; m < m0 + 32; ++m) {
            int d = s_dest[m];
            float v = s_outf[m * OUT_LD + c];
            if (d != cur) {
                if (cur >= 0) {
                    float* p = &out[(size_t)cur * (2 * OUTD) + colbase + c];
                    if (rs > m0) *p = run; else atomicAdd(p, run);
                }
                cur = d; run = 0.f; rs = m;
            }
            if (d >= 0) run += v;
        }
        if (cur >= 0)
            atomicAdd(&out[(size_t)cur * (2 * OUTD) + colbase + c], run);
    }
}

extern "C" void kernel_launch(void* const* d_in, const int* in_sizes, int n_in,
                              void* d_out, int out_size, void* d_ws, size_t ws_size,
                              hipStream_t stream) {
    const float* x   = (const float*)d_in[0];
    const int*   ei  = (const int*)d_in[1];
    const float* ea  = (const float*)d_in[2];
    const float* W1o = (const float*)d_in[3];
    const float* b1o = (const float*)d_in[4];
    const float* W2o = (const float*)d_in[5];
    const float* b2o = (const float*)d_in[6];
    const float* W1i = (const float*)d_in[7];
    const float* b1i = (const float*)d_in[8];
    const float* W2i = (const float*)d_in[9];
    const float* b2i = (const float*)d_in[10];
    float* out = (float*)d_out;
    const int E = in_sizes[1] / 2;
    const int N = in_sizes[0] / DN;
    const int nch = (N + 1023) >> 10;          // chunks per branch (<=64 assumed)

    // workspace layout (16B alignment holds: all int counts are multiples of 4)
    int* cnt      = (int*)d_ws;                // 2 (+pad to 16)
    int* chunkSum = cnt + 16;                  // 2*nch (<=128)
    int* hist     = chunkSum + 128;            // 2N
    int* cursor   = hist + 2 * (size_t)N;      // 2N
    int* list_out = cursor + 2 * (size_t)N;    // E
    int* list_in  = list_out + E;              // E
    unsigned short* W1po = (unsigned short*)(list_in + E);
    unsigned short* W1pi = W1po + DIN * HID;
    unsigned short* W2po = W1pi + DIN * HID;
    unsigned short* W2pi = W2po + HID * OUTD;
    unsigned short* xb   = W2pi + HID * OUTD;  // N*DN bf16

    hipMemsetAsync(d_out, 0, (size_t)out_size * sizeof(float), stream);
    hipMemsetAsync(d_ws, 0, (576 + 8 * (size_t)N), stream);   // cnt+chunkSum+hist

    const int PACKN = 2 * DIN * HID + 2 * HID * OUTD;
    const int prepN = PACKN + E + N * DN / 8;
    prep_kernel<<<(prepN + 255) / 256, 256, 0, stream>>>(
        W1o, W1i, W2o, W2i, W1po, W1pi, W2po, W2pi, ei, E, N, hist, x, xb);

    scan1_kernel<<<2 * nch, 1024, 0, stream>>>(hist, cursor, chunkSum, N, nch);
    scan2_kernel<<<1, 128, 0, stream>>>(chunkSum, cnt, nch);
    reorder_kernel<<<(E + 255) / 256, 256, 0, stream>>>(
        ei, E, N, nch, cursor, chunkSum, list_out, list_in);

    const int nbpb = (E + TE - 1) / TE;
    mlp_scatter_kernel<<<2 * nbpb, 256, 0, stream>>>(
        xb, ei, ea, W1po, W1pi, b1o, b1i, W2po, W2pi, b2o, b2i,
        list_out, list_in, cnt, out, E, nbpb);
}

// Round 5
// 573.713 us; speedup vs baseline: 1.9950x; 1.0519x over previous
//
#include <hip/hip_runtime.h>
#include <hip/hip_bf16.h>

typedef __attribute__((ext_vector_type(8))) short short8;
typedef __attribute__((ext_vector_type(8))) unsigned short ushort8;
typedef __attribute__((ext_vector_type(4))) float f32x4;

#define DN   128
#define DE   64
#define DIN  192
#define HID  256
#define OUTD 128
#define TE   128     // edges per block
#define NT   512     // threads per block (8 waves)
#define MSG_LD 200   // 192 + 8 pad (bf16): row stride 400B -> 4-dword bank shift/row
#define H_LD   264   // 256 + 8 pad (bf16): row stride 528B -> 4-dword bank shift/row
#define OUT_LD 132   // f32 out tile stride (128 + 4)

static __device__ __forceinline__ unsigned short f2b(float f) {
    unsigned int u = __float_as_uint(f);
    u += 0x7fffu + ((u >> 16) & 1u);
    return (unsigned short)(u >> 16);
}

// Fused prep: (a) pack 4 weight mats to bf16 fragment layout Wp[((k/32)*Nc+n)*32+(k%32)],
// (b) histogram dest rows per branch, (c) convert x to bf16.
__global__ __launch_bounds__(256)
void prep_kernel(const float* __restrict__ W1o, const float* __restrict__ W1i,
                 const float* __restrict__ W2o, const float* __restrict__ W2i,
                 unsigned short* __restrict__ W1po, unsigned short* __restrict__ W1pi,
                 unsigned short* __restrict__ W2po, unsigned short* __restrict__ W2pi,
                 const int* __restrict__ ei, int E, int N, int* __restrict__ hist,
                 const float* __restrict__ x, unsigned short* __restrict__ xb) {
    const int S1 = DIN * HID, S2v = HID * OUTD;
    const int PACKN = 2 * S1 + 2 * S2v;
    int idx = blockIdx.x * blockDim.x + threadIdx.x;
    if (idx < PACKN) {
        const float* W; unsigned short* Wp; int Nc, j;
        if      (idx < S1)          { W = W1o; Wp = W1po; Nc = HID;  j = idx; }
        else if (idx < 2*S1)        { W = W1i; Wp = W1pi; Nc = HID;  j = idx - S1; }
        else if (idx < 2*S1 + S2v)  { W = W2o; Wp = W2po; Nc = OUTD; j = idx - 2*S1; }
        else                        { W = W2i; Wp = W2pi; Nc = OUTD; j = idx - 2*S1 - S2v; }
        int k = j / Nc, n = j - k * Nc;
        Wp[(((k >> 5) * Nc + n) << 5) + (k & 31)] = f2b(W[j]);
    } else if (idx < PACKN + E) {
        int e = idx - PACKN;
        int r = ei[e], c = ei[E + e];
        if      (r < c) atomicAdd(&hist[r], 1);
        else if (r > c) atomicAdd(&hist[N + r], 1);
    } else {
        int i = idx - PACKN - E;           // 8 x-floats per thread
        if (i < N * DN / 8) {
            float4 a = reinterpret_cast<const float4*>(x)[i * 2];
            float4 b = reinterpret_cast<const float4*>(x)[i * 2 + 1];
            ushort8 v = { f2b(a.x), f2b(a.y), f2b(a.z), f2b(a.w),
                          f2b(b.x), f2b(b.y), f2b(b.z), f2b(b.w) };
            reinterpret_cast<ushort8*>(xb)[i] = v;
        }
    }
}

// Per-chunk (1024 rows) exclusive scan of one branch's histogram.
__global__ __launch_bounds__(1024)
void scan1_kernel(const int* __restrict__ hist, int* __restrict__ cursor,
                  int* __restrict__ chunkSum, int N, int nch) {
    __shared__ int s_ws[16];
    const int br = blockIdx.x / nch, ch = blockIdx.x - br * nch;
    const int tid = threadIdx.x, lane = tid & 63, wv = tid >> 6;
    const int i = ch * 1024 + tid;
    int v = (i < N) ? hist[(size_t)br * N + i] : 0;
    int incl = v;
    #pragma unroll
    for (int d = 1; d < 64; d <<= 1) {
        int t = __shfl_up(incl, d, 64);
        if (lane >= d) incl += t;
    }
    if (lane == 63) s_ws[wv] = incl;
    __syncthreads();
    if (tid < 16) {
        int w = s_ws[tid];
        int wi = w;
        #pragma unroll
        for (int d = 1; d < 16; d <<= 1) {
            int t = __shfl_up(wi, d, 64);
            if (tid >= d) wi += t;
        }
        s_ws[tid] = wi - w;
    }
    __syncthreads();
    int excl = s_ws[wv] + incl - v;
    if (i < N) cursor[(size_t)br * N + i] = excl;
    if (tid == 1023) chunkSum[br * nch + ch] = excl + v;
}

// Scan chunk sums (nch <= 64 per branch): wave 0 -> branch 0, wave 1 -> branch 1.
__global__ __launch_bounds__(128)
void scan2_kernel(int* __restrict__ chunkSum, int* __restrict__ cnt, int nch) {
    const int br = threadIdx.x >> 6, lane = threadIdx.x & 63;
    int v = (lane < nch) ? chunkSum[br * nch + lane] : 0;
    int incl = v;
    #pragma unroll
    for (int d = 1; d < 64; d <<= 1) {
        int t = __shfl_up(incl, d, 64);
        if (lane >= d) incl += t;
    }
    if (lane < nch) chunkSum[br * nch + lane] = incl - v;
    if (lane == nch - 1) cnt[br] = incl;
}

// Scatter edges to sorted-by-dest-row positions.
__global__ __launch_bounds__(256)
void reorder_kernel(const int* __restrict__ ei, int E, int N, int nch,
                    int* __restrict__ cursor, const int* __restrict__ chunkSum,
                    int* __restrict__ list_out, int* __restrict__ list_in) {
    int e = blockIdx.x * blockDim.x + threadIdx.x;
    if (e >= E) return;
    int r = ei[e], c = ei[E + e];
    if (r == c) return;
    int br = (r < c) ? 0 : 1;
    int p = chunkSum[br * nch + (r >> 10)] + atomicAdd(&cursor[(size_t)br * N + r], 1);
    (br ? list_in : list_out)[p] = e;
}

__global__ __launch_bounds__(NT, 4)
void mlp_scatter_kernel(const unsigned short* __restrict__ xb,
                        const int* __restrict__ ei,
                        const float* __restrict__ ea,
                        const unsigned short* __restrict__ W1p_out,
                        const unsigned short* __restrict__ W1p_in,
                        const float* __restrict__ b1_out,
                        const float* __restrict__ b1_in,
                        const unsigned short* __restrict__ W2p_out,
                        const unsigned short* __restrict__ W2p_in,
                        const float* __restrict__ b2_out,
                        const float* __restrict__ b2_in,
                        const int* __restrict__ list_out,
                        const int* __restrict__ list_in,
                        const int* __restrict__ cnt,
                        float* __restrict__ out,
                        int E, int nbpb) {
    // Union buffer, 67584 B: msg bf16 (128x200) -> h bf16 (128x264) -> out f32 (128x132).
    __shared__ __align__(16) unsigned short s_buf[TE * H_LD];
    __shared__ int s_eid[TE], s_dest[TE], s_col[TE];

    const int branch = (blockIdx.x >= nbpb) ? 1 : 0;   // 0 = out-flow, 1 = in-flow
    const int lb = blockIdx.x - branch * nbpb;
    const int count = cnt[branch];
    if (lb * TE >= count) return;
    const int* list            = branch ? list_in : list_out;
    const unsigned short* W1p  = branch ? W1p_in  : W1p_out;
    const float* b1            = branch ? b1_in   : b1_out;
    const unsigned short* W2p  = branch ? W2p_in  : W2p_out;
    const float* b2            = branch ? b2_in   : b2_out;
    const int colbase          = branch ? 0 : OUTD;  // out = concat(flow_in, flow_out)

    const int tid = threadIdx.x;
    if (tid < TE) {
        int idx = lb * TE + tid;
        int e = (idx < count) ? list[idx] : -1;
        s_eid[tid]  = e;
        s_dest[tid] = (e >= 0) ? ei[e] : -1;       // sorted non-decreasing dest rows
        s_col[tid]  = (e >= 0) ? ei[E + e] : 0;
    }
    __syncthreads();

    // Gather msg = concat(xb[col] (bf16), f2b(edge_attr[e])) into LDS. 4 threads/edge.
    {
        const int le  = tid >> 2;
        const int sub = tid & 3;
        const int e   = s_eid[le];
        const ushort8* xrow = reinterpret_cast<const ushort8*>(xb) + (size_t)s_col[le] * (DN / 8);
        #pragma unroll
        for (int j = 0; j < 4; ++j) {
            int seg = sub + j * 4;                       // elems [seg*8, seg*8+8)
            ushort8 v = {0, 0, 0, 0, 0, 0, 0, 0};
            if (e >= 0) v = xrow[seg];
            *reinterpret_cast<ushort8*>(&s_buf[le * MSG_LD + seg * 8]) = v;
        }
        const float4* erow = reinterpret_cast<const float4*>(ea) + (size_t)e * (DE / 4);
        #pragma unroll
        for (int j = 0; j < 4; ++j) {
            float4 v = make_float4(0.f, 0.f, 0.f, 0.f);
            if (e >= 0) v = erow[sub * 4 + j];
            unsigned int lo = (unsigned int)f2b(v.x) | ((unsigned int)f2b(v.y) << 16);
            unsigned int hi = (unsigned int)f2b(v.z) | ((unsigned int)f2b(v.w) << 16);
            *reinterpret_cast<uint2*>(&s_buf[le * MSG_LD + DN + sub * 16 + j * 4]) = make_uint2(lo, hi);
        }
    }
    __syncthreads();

    const int wave = tid >> 6;
    const int lane = tid & 63;
    const int ln   = lane & 15;
    const int quad = lane >> 4;

    // ---- GEMM1: h = relu(msg @ W1 + b1).  M=128 (8 m-frags), N=256 (32/wave), K=192.
    f32x4 acc[8][2];
    {
        const int nbase = wave * 32;
        float bias[2];
        #pragma unroll
        for (int t = 0; t < 2; ++t) bias[t] = b1[nbase + t * 16 + ln];
        #pragma unroll
        for (int mt = 0; mt < 8; ++mt)
            #pragma unroll
            for (int t = 0; t < 2; ++t)
                acc[mt][t] = (f32x4){bias[t], bias[t], bias[t], bias[t]};
        #pragma unroll
        for (int kt = 0; kt < DIN / 32; ++kt) {
            short8 a[8], b[2];
            #pragma unroll
            for (int mt = 0; mt < 8; ++mt)
                a[mt] = *reinterpret_cast<const short8*>(
                    &s_buf[(mt * 16 + ln) * MSG_LD + kt * 32 + quad * 8]);
            #pragma unroll
            for (int t = 0; t < 2; ++t)
                b[t] = *reinterpret_cast<const short8*>(
                    &W1p[((kt * HID + nbase + t * 16 + ln) << 5) + quad * 8]);
            #pragma unroll
            for (int mt = 0; mt < 8; ++mt)
                #pragma unroll
                for (int t = 0; t < 2; ++t)
                    acc[mt][t] = __builtin_amdgcn_mfma_f32_16x16x32_bf16(a[mt], b[t], acc[mt][t], 0, 0, 0);
        }
    }
    __syncthreads();   // msg reads done; s_buf re-used for h

    // ReLU -> bf16 h into s_buf (stride H_LD). C/D map: col=lane&15, row=quad*4+reg.
    {
        const int nbase = wave * 32;
        #pragma unroll
        for (int mt = 0; mt < 8; ++mt)
            #pragma unroll
            for (int t = 0; t < 2; ++t) {
                int ncol = nbase + t * 16 + ln;
                #pragma unroll
                for (int r = 0; r < 4; ++r) {
                    int m = mt * 16 + quad * 4 + r;
                    float v = acc[mt][t][r];
                    s_buf[m * H_LD + ncol] = f2b(v > 0.f ? v : 0.f);
                }
            }
    }
    __syncthreads();

    // ---- GEMM2: o = h @ W2 + b2.  M=128, N=128 (16/wave), K=256.
    f32x4 acc2[8];
    {
        const int nbase = wave * 16;
        float bias2 = b2[nbase + ln];
        #pragma unroll
        for (int mt = 0; mt < 8; ++mt)
            acc2[mt] = (f32x4){bias2, bias2, bias2, bias2};
        #pragma unroll
        for (int kt = 0; kt < HID / 32; ++kt) {
            short8 a[8], b;
            #pragma unroll
            for (int mt = 0; mt < 8; ++mt)
                a[mt] = *reinterpret_cast<const short8*>(
                    &s_buf[(mt * 16 + ln) * H_LD + kt * 32 + quad * 8]);
            b = *reinterpret_cast<const short8*>(
                &W2p[((kt * OUTD + nbase + ln) << 5) + quad * 8]);
            #pragma unroll
            for (int mt = 0; mt < 8; ++mt)
                acc2[mt] = __builtin_amdgcn_mfma_f32_16x16x32_bf16(a[mt], b, acc2[mt], 0, 0, 0);
        }
    }
    __syncthreads();   // h reads done; s_buf re-used for f32 out tile

    float* s_outf = reinterpret_cast<float*>(s_buf);
    {
        const int nbase = wave * 16;
        #pragma unroll
        for (int mt = 0; mt < 8; ++mt)
            #pragma unroll
            for (int r = 0; r < 4; ++r)
                s_outf[(mt * 16 + quad * 4 + r) * OUT_LD + nbase + ln] = acc2[mt][r];
    }
    __syncthreads();

    // Segment-reduce over sorted dest rows. Runs strictly interior to this
    // thread's row-range are sole-owner (global sort!) -> plain store; boundary -> atomic.
    {
        const int c  = tid & 127;
        const int m0 = (tid >> 7) * 32;
        float run = 0.f;
        int cur = -1, rs = m0;
        for (int m = m0; m < m0 + 32; ++m) {
            int d = s_dest[m];
            float v = s_outf[m * OUT_LD + c];
            if (d != cur) {
                if (cur >= 0) {
                    float* p = &out[(size_t)cur * (2 * OUTD) + colbase + c];
                    if (rs > m0) *p = run; else atomicAdd(p, run);
                }
                cur = d; run = 0.f; rs = m;
            }
            if (d >= 0) run += v;
        }
        if (cur >= 0)
            atomicAdd(&out[(size_t)cur * (2 * OUTD) + colbase + c], run);
    }
}

extern "C" void kernel_launch(void* const* d_in, const int* in_sizes, int n_in,
                              void* d_out, int out_size, void* d_ws, size_t ws_size,
                              hipStream_t stream) {
    const float* x   = (const float*)d_in[0];
    const int*   ei  = (const int*)d_in[1];
    const float* ea  = (const float*)d_in[2];
    const float* W1o = (const float*)d_in[3];
    const float* b1o = (const float*)d_in[4];
    const float* W2o = (const float*)d_in[5];
    const float* b2o = (const float*)d_in[6];
    const float* W1i = (const float*)d_in[7];
    const float* b1i = (const float*)d_in[8];
    const float* W2i = (const float*)d_in[9];
    const float* b2i = (const float*)d_in[10];
    float* out = (float*)d_out;
    const int E = in_sizes[1] / 2;
    const int N = in_sizes[0] / DN;
    const int nch = (N + 1023) >> 10;          // chunks per branch (<=64 assumed)

    // workspace layout
    int* cnt      = (int*)d_ws;                // 2 (+pad to 16)
    int* chunkSum = cnt + 16;                  // 2*nch (<=128)
    int* hist     = chunkSum + 128;            // 2N
    int* cursor   = hist + 2 * (size_t)N;      // 2N
    int* list_out = cursor + 2 * (size_t)N;    // E
    int* list_in  = list_out + E;              // E
    unsigned short* W1po = (unsigned short*)(list_in + E);
    unsigned short* W1pi = W1po + DIN * HID;
    unsigned short* W2po = W1pi + DIN * HID;
    unsigned short* W2pi = W2po + HID * OUTD;
    unsigned short* xb   = W2pi + HID * OUTD;  // N*DN bf16

    hipMemsetAsync(d_out, 0, (size_t)out_size * sizeof(float), stream);
    hipMemsetAsync(d_ws, 0, (576 + 8 * (size_t)N), stream);   // cnt+chunkSum+hist

    const int PACKN = 2 * DIN * HID + 2 * HID * OUTD;
    const int prepN = PACKN + E + N * DN / 8;
    prep_kernel<<<(prepN + 255) / 256, 256, 0, stream>>>(
        W1o, W1i, W2o, W2i, W1po, W1pi, W2po, W2pi, ei, E, N, hist, x, xb);

    scan1_kernel<<<2 * nch, 1024, 0, stream>>>(hist, cursor, chunkSum, N, nch);
    scan2_kernel<<<1, 128, 0, stream>>>(chunkSum, cnt, nch);
    reorder_kernel<<<(E + 255) / 256, 256, 0, stream>>>(
        ei, E, N, nch, cursor, chunkSum, list_out, list_in);

    const int nbpb = (E + TE - 1) / TE;
    mlp_scatter_kernel<<<2 * nbpb, NT, 0, stream>>>(
        xb, ei, ea, W1po, W1pi, b1o, b1i, W2po, W2pi, b2o, b2i,
        list_out, list_in, cnt, out, E, nbpb);
}